// Round 2
// 528.069 us; speedup vs baseline: 1.0636x; 1.0636x over previous
//
#include <hip/hip_runtime.h>

namespace {

constexpr int Gg     = 160;
constexpr int NA     = 3;
constexpr int NB     = 16;
constexpr int CP     = 86;          // channels per anchor: 6 + 80
constexpr int NCLS   = 80;
constexpr int PLANE  = Gg * Gg;     // 25600
constexpr int QPP    = PLANE / 4;   // 6400 quads per (b,a) plane
constexpr int TOTAL  = NB * NA * QPP;
constexpr float STRIDE = 8.0f;      // 1280 / 160
constexpr int LROW   = 29;          // 28 outputs padded to 29 floats (bank spread)

typedef float f4 __attribute__((ext_vector_type(4)));   // native vec: ok for nontemporal builtins

union F4 { f4 v; float f[4]; };

__device__ __forceinline__ f4 ldnt(const float* p) {
    return __builtin_nontemporal_load(reinterpret_cast<const f4*>(p));
}

__device__ __forceinline__ float fsigmoid(float v) {
    // 1/(1+e^-v) with fast exp + hw rcp; |v| stays far below overflow.
    return __builtin_amdgcn_rcpf(1.0f + __expf(-v));
}

__global__ __launch_bounds__(256, 6) void anchor_decode(
    const float* __restrict__ x,
    const float* __restrict__ anchors,
    float* __restrict__ out)
{
    // per-thread 28-float output row, padded to 29 for LDS bank spread
    __shared__ float lds[256 * LROW];   // 29,696 B

    const int t    = blockIdx.x * 256 + threadIdx.x;
    const int lane = threadIdx.x & 63;

    const int q   = t % QPP;
    const int ba  = t / QPP;           // b*NA + a   (uniform within a wave: QPP % 64 == 0)
    const int a   = ba - (ba / NA) * NA;
    const int pix = q * 4;
    const int i   = pix / Gg;          // grid_y
    const int j   = pix - i * Gg;      // grid_x of first pixel (row-aligned: 160 % 4 == 0)

    const float* xp = x + (size_t)ba * (CP * PLANE) + pix;
    const float* cp = xp + (size_t)6 * PLANE;     // class channels base

    // ---------- phase 1: streaming argmax over 80 class channels ----------
    // lean register set: 8 state + 32 in-flight data
    float bval[4], bidx[4];
    #pragma unroll
    for (int p = 0; p < 4; ++p) { bval[p] = -__builtin_inff(); bidx[p] = 0.0f; }

    for (int c0 = 0; c0 < NCLS; c0 += 8) {
        F4 u[8];
        #pragma unroll
        for (int k = 0; k < 8; ++k)
            u[k].v = ldnt(cp + (size_t)(c0 + k) * PLANE);
        #pragma unroll
        for (int k = 0; k < 8; ++k) {
            const float fc = (float)(c0 + k);
            #pragma unroll
            for (int p = 0; p < 4; ++p) {
                const bool gt = u[k].f[p] > bval[p];   // strict > keeps first max
                bval[p] = gt ? u[k].f[p] : bval[p];
                bidx[p] = gt ? fc : bidx[p];
            }
        }
    }

    // ---------- phase 2: head channels + decode math ----------
    F4 h0, h1, h2, h3, h4, h5;
    h0.v = ldnt(xp + 0 * PLANE);
    h1.v = ldnt(xp + 1 * PLANE);
    h2.v = ldnt(xp + 2 * PLANE);
    h3.v = ldnt(xp + 3 * PLANE);
    h4.v = ldnt(xp + 4 * PLANE);
    h5.v = ldnt(xp + 5 * PLANE);

    const float aw = anchors[a * 2 + 0];
    const float ah = anchors[a * 2 + 1];
    const float fi = (float)i;
    const float fj = (float)j;

    float* lrow = lds + (size_t)threadIdx.x * LROW;
    #pragma unroll
    for (int p = 0; p < 4; ++p) {
        lrow[p * 7 + 0] = floorf((fsigmoid(h0.f[p]) + (fj + (float)p)) * STRIDE);
        lrow[p * 7 + 1] = floorf((fsigmoid(h1.f[p]) + fi) * STRIDE);
        lrow[p * 7 + 2] = __expf(h2.f[p]) * aw;
        lrow[p * 7 + 3] = __expf(h3.f[p]) * ah;
        lrow[p * 7 + 4] = h4.f[p];
        lrow[p * 7 + 5] = fsigmoid(h5.f[p]);
        lrow[p * 7 + 6] = bidx[p];
    }

    __syncthreads();

    // ---------- phase 3: wave-transposed, fully-coalesced 1 KB stores ----------
    const int wv = threadIdx.x >> 6;
    const float* wbase = lds + (size_t)wv * 64 * LROW;
    const int q0 = q - lane;   // lane 0's quad in this wave (same ba for all lanes)
    float* op = out + ((size_t)ba * PLANE + (size_t)q0 * 4) * 7;

    #pragma unroll
    for (int k = 0; k < 7; ++k) {
        F4 w;
        #pragma unroll
        for (int e = 0; e < 4; ++e) {
            const int f = k * 256 + lane * 4 + e;          // float index in wave's 1792-float region
            w.f[e] = wbase[(f / 28) * LROW + (f % 28)];    // owner-lane row, element
        }
        __builtin_nontemporal_store(
            w.v, reinterpret_cast<f4*>(op + k * 256 + lane * 4));
    }
}

} // namespace

extern "C" void kernel_launch(void* const* d_in, const int* in_sizes, int n_in,
                              void* d_out, int out_size, void* d_ws, size_t ws_size,
                              hipStream_t stream) {
    const float* x       = (const float*)d_in[0];
    // d_in[1] (target) is unused by the reference output
    const float* anchors = (const float*)d_in[2];
    float* out           = (float*)d_out;

    const int blocks = (TOTAL + 255) / 256;  // 1200
    anchor_decode<<<blocks, 256, 0, stream>>>(x, anchors, out);
}

// Round 3
// 523.042 us; speedup vs baseline: 1.0739x; 1.0096x over previous
//
#include <hip/hip_runtime.h>

namespace {

constexpr int Gg     = 160;
constexpr int NA     = 3;
constexpr int NB     = 16;
constexpr int CP     = 86;          // channels per anchor: 6 + 80
constexpr int NCLS   = 80;
constexpr int PLANE  = Gg * Gg;     // 25600
constexpr int BPX    = 1024;        // pixels per (single-wave) block
constexpr int BLKPP  = PLANE / BPX; // 25 blocks per (b,a) plane
constexpr int NBLK   = NB * NA * BLKPP;  // 1200
constexpr float STRIDE = 8.0f;      // 1280 / 160
constexpr int LROW   = 29;          // 28 outputs padded to 29 floats (bank spread)

typedef float f4 __attribute__((ext_vector_type(4)));   // native vec for nontemporal builtins

union F4 { f4 v; float f[4]; };

__device__ __forceinline__ f4 ldnt(const float* p) {
    return __builtin_nontemporal_load(reinterpret_cast<const f4*>(p));
}
__device__ __forceinline__ void stnt(float* p, f4 v) {
    __builtin_nontemporal_store(v, reinterpret_cast<f4*>(p));
}
__device__ __forceinline__ float fsigmoid(float v) {
    // 1/(1+e^-v) with fast exp + hw rcp; |v| stays far below overflow.
    return __builtin_amdgcn_rcpf(1.0f + __expf(-v));
}

// One wave (64 threads) per block; each thread owns 4 quads (16 px) so that a
// wave reads 4 KB CONTIGUOUS per channel (4 back-to-back 1KB dwordx4 loads):
// quad k of lane l covers pixels P0 + k*256 + l*4 .. +3.
__global__ __launch_bounds__(64) void anchor_decode(
    const float* __restrict__ x,
    const float* __restrict__ anchors,
    float* __restrict__ out)
{
    __shared__ float lds[256 * LROW];   // 256 quad-rows of 28(+1) floats = 29,696 B

    const int tid = threadIdx.x;
    const int bid = blockIdx.x;
    const int ba  = bid / BLKPP;        // b*NA + a
    const int blk = bid - ba * BLKPP;
    const int a   = ba % NA;
    const int P0  = blk * BPX;

    const float* base  = x + (size_t)ba * (CP * PLANE) + P0 + tid * 4;
    const float* cbase = base + (size_t)6 * PLANE;   // class channels

    // ---------- phase 1: streaming argmax over 80 class channels ----------
    float bval[4][4], bidx[4][4];
    #pragma unroll
    for (int k = 0; k < 4; ++k)
        #pragma unroll
        for (int p = 0; p < 4; ++p) { bval[k][p] = -__builtin_inff(); bidx[k][p] = 0.0f; }

    F4 cur[4], nxt[4];
    #pragma unroll
    for (int k = 0; k < 4; ++k) cur[k].v = ldnt(cbase + k * 256);
    #pragma unroll
    for (int k = 0; k < 4; ++k) nxt[k] = cur[k];   // defined value for the tail rotate

    #pragma unroll 4
    for (int c = 0; c < NCLS; ++c) {
        if (c + 1 < NCLS) {            // lookahead: next channel's 4 KB in flight
            const float* np = cbase + (size_t)(c + 1) * PLANE;
            #pragma unroll
            for (int k = 0; k < 4; ++k) nxt[k].v = ldnt(np + k * 256);
        }
        const float fc = (float)c;
        #pragma unroll
        for (int k = 0; k < 4; ++k)
            #pragma unroll
            for (int p = 0; p < 4; ++p) {
                const bool gt = cur[k].f[p] > bval[k][p];   // strict > keeps first max
                bval[k][p] = gt ? cur[k].f[p] : bval[k][p];
                bidx[k][p] = gt ? fc : bidx[k][p];
            }
        #pragma unroll
        for (int k = 0; k < 4; ++k) cur[k] = nxt[k];
    }

    // ---------- phase 2: head channels + decode math ----------
    F4 h[6][4];
    #pragma unroll
    for (int c = 0; c < 6; ++c)
        #pragma unroll
        for (int k = 0; k < 4; ++k)
            h[c][k].v = ldnt(base + (size_t)c * PLANE + k * 256);

    const float aw = anchors[a * 2 + 0];
    const float ah = anchors[a * 2 + 1];

    #pragma unroll
    for (int k = 0; k < 4; ++k) {
        const int pix = P0 + k * 256 + tid * 4;   // pix%4==0, 160%4==0 -> quad stays in one row
        const int i   = pix / Gg;                 // grid_y
        const int j   = pix - i * Gg;             // grid_x of first pixel
        const float fi = (float)i;
        const float fj = (float)j;
        float* lr = lds + (size_t)(k * 64 + tid) * LROW;   // row ordered by local pixel/4
        #pragma unroll
        for (int p = 0; p < 4; ++p) {
            lr[p * 7 + 0] = floorf((fsigmoid(h[0][k].f[p]) + (fj + (float)p)) * STRIDE);
            lr[p * 7 + 1] = floorf((fsigmoid(h[1][k].f[p]) + fi) * STRIDE);
            lr[p * 7 + 2] = __expf(h[2][k].f[p]) * aw;
            lr[p * 7 + 3] = __expf(h[3][k].f[p]) * ah;
            lr[p * 7 + 4] = h[4][k].f[p];
            lr[p * 7 + 5] = fsigmoid(h[5][k].f[p]);
            lr[p * 7 + 6] = bidx[k][p];
        }
    }

    __syncthreads();

    // ---------- phase 3: block-transposed, fully-coalesced 1 KB stores ----------
    // block's out region = 1024 px * 7 = 7168 contiguous floats = 28 chunks of 1 KB
    const size_t obase = ((size_t)ba * PLANE + P0) * 7;
    #pragma unroll
    for (int c = 0; c < 28; ++c) {
        F4 w;
        #pragma unroll
        for (int e = 0; e < 4; ++e) {
            const int o = c * 256 + tid * 4 + e;            // float index in block region
            w.f[e] = lds[(o / 28) * LROW + (o % 28)];       // owner quad-row, element
        }
        stnt(out + obase + c * 256 + tid * 4, w.v);
    }
}

} // namespace

extern "C" void kernel_launch(void* const* d_in, const int* in_sizes, int n_in,
                              void* d_out, int out_size, void* d_ws, size_t ws_size,
                              hipStream_t stream) {
    const float* x       = (const float*)d_in[0];
    // d_in[1] (target) is unused by the reference output
    const float* anchors = (const float*)d_in[2];
    float* out           = (float*)d_out;

    anchor_decode<<<NBLK, 64, 0, stream>>>(x, anchors, out);  // 1200 single-wave blocks
}